// Round 3
// baseline (309.687 us; speedup 1.0000x reference)
//
#include <hip/hip_runtime.h>
#include <math.h>

#define TPB 256
#define W 64
#define H 64

typedef float f32x4 __attribute__((ext_vector_type(4)));

__device__ __forceinline__ f32x4 max4(f32x4 a, f32x4 b) {
    f32x4 r;
    r.x = fmaxf(a.x, b.x); r.y = fmaxf(a.y, b.y);
    r.z = fmaxf(a.z, b.z); r.w = fmaxf(a.w, b.w);
    return r;
}

// DPP row shifts within 16-lane rows. Our col-group g = lane&15, so lane i-1 /
// i+1 inside a DPP row IS the x-neighbor strip; the row boundary (g==0 / g==15)
// is exactly the image edge, which we mask to -inf anyway. VALU-pipe: replaces
// 112 ds_bpermute per thread with v_mov_b32 dpp — zero DS traffic, no LDS.
__device__ __forceinline__ float dpp_shr1(float v) {  // lane i <- lane i-1
    return __int_as_float(__builtin_amdgcn_update_dpp(
        0, __float_as_int(v), 0x111, 0xf, 0xf, true));  // row_shr:1
}
__device__ __forceinline__ float dpp_shl1(float v) {  // lane i <- lane i+1
    return __int_as_float(__builtin_amdgcn_update_dpp(
        0, __float_as_int(v), 0x101, 0xf, 0xf, true));  // row_shl:1
}

// One image per block, one 4x4 output tile per thread, NO LDS / NO barriers:
// each thread loads its own 16-row vertical halo (4x read amplification served
// by L1/L2; HBM still reads each image exactly once). Waves run fully
// desynchronized -> store issue spreads out instead of phase-locked bursts.
__global__ __launch_bounds__(TPB, 3) void spp_kernel(const float* __restrict__ in,
                                                     float* __restrict__ out) {
    const int tid = threadIdx.x;
    const int img = blockIdx.x;
    const int g   = tid & 15;            // col group: x = 4g..4g+3
    const int h   = tid >> 4;            // row group: y = 4h..4h+3
    const int x0  = g << 2;
    const int y0  = h << 2;
    const bool qlo = (g == 0);
    const bool qhi = (g == 15);
    const float NEG = -INFINITY;
    const f32x4 NEG4 = {NEG, NEG, NEG, NEG};

    const size_t pstr  = (size_t)256 * H * W;
    const size_t obase = (((size_t)(img >> 8)) * 1024 + (img & 255)) * (size_t)(H * W);
    const float* ibase = in + (size_t)img * (H * W);

    // ---- load rows y0-6 .. y0+9 of own 4-col strip (clamped), all 16 in flight ----
    f32x4 rw[16];
    #pragma unroll
    for (int j = 0; j < 16; ++j) {
        const int y  = y0 - 6 + j;
        const int yc = y < 0 ? 0 : (y > 63 ? 63 : y);
        rw[j] = *(const f32x4*)(ibase + yc * W + x0);
    }
    #pragma unroll
    for (int j = 0; j < 16; ++j) {
        const int y = y0 - 6 + j;
        if (y < 0 || y > 63) rw[j] = NEG4;   // -inf pad (matches torch implicit -inf)
    }

    // ---- pool0 = x: raw rows y0..y0+3 are rw[6..9] ----
    float* o0 = out + obase;
    #pragma unroll
    for (int i = 0; i < 4; ++i)
        __builtin_nontemporal_store(rw[6 + i], (f32x4*)(o0 + (y0 + i) * W + x0));

    // ---- row-max-5 in place: halo x0-2..x0+5 via DPP, edges -> -inf ----
    #pragma unroll
    for (int j = 0; j < 16; ++j) {
        const f32x4 t = rw[j];
        float e0 = dpp_shr1(t.z), e1 = dpp_shr1(t.w);   // x0-2, x0-1
        float e6 = dpp_shl1(t.x), e7 = dpp_shl1(t.y);   // x0+4, x0+5
        if (qlo) { e0 = NEG; e1 = NEG; }
        if (qhi) { e6 = NEG; e7 = NEG; }
        const float p0 = fmaxf(e0, e1),  p1 = fmaxf(e1, t.x), p2 = fmaxf(t.x, t.y);
        const float p3 = fmaxf(t.y, t.z), p4 = fmaxf(t.z, t.w), p5 = fmaxf(t.w, e6);
        f32x4 r;                           // r5 at x0..x0+3
        r.x = fmaxf(fmaxf(p0, p2), t.z);
        r.y = fmaxf(fmaxf(p1, p3), t.w);
        r.z = fmaxf(fmaxf(p2, p4), e6);
        r.w = fmaxf(fmaxf(p3, p5), e7);
        rw[j] = r;
    }

    // ---- vertical: col5[t] = max(r5[t..t+4]), t=0..11 (rolling m2 window) ----
    f32x4 col5[12];
    {
        f32x4 m2a = max4(rw[0], rw[1]);
        f32x4 m2b = max4(rw[1], rw[2]);
        #pragma unroll
        for (int t = 0; t < 12; ++t) {
            const f32x4 m2c = max4(rw[t + 2], rw[t + 3]);
            col5[t] = max4(max4(m2a, m2c), rw[t + 4]);
            m2a = m2b; m2b = m2c;
        }
    }

    // ---- outputs: pool5 direct; pool9/13 via widening on already-5-wide cols ----
    float* o5  = out + obase +     pstr;
    float* o9  = out + obase + 2 * pstr;
    float* o13 = out + obase + 3 * pstr;
    #pragma unroll
    for (int i = 0; i < 4; ++i) {
        const f32x4 c5  = col5[i + 4];                               // 5 rows x 5 cols
        const f32x4 c9  = max4(col5[i + 2], col5[i + 6]);            // 9 rows x 5 cols
        const f32x4 c13 = max4(max4(col5[i], col5[i + 4]), col5[i + 8]); // 13 x 5

        __builtin_nontemporal_store(c5, (f32x4*)(o5 + (y0 + i) * W + x0));

        // pool9: out[x] = max(c9[x-2], c9[x+2])
        const float Lz = dpp_shr1(c9.z);
        const float Lw = dpp_shr1(c9.w);
        const float Rx = dpp_shl1(c9.x);
        const float Ry = dpp_shl1(c9.y);
        const f32x4 lh9 = qlo ? (f32x4){c9.x, c9.x, c9.x, c9.y}
                              : (f32x4){Lz, Lw, c9.x, c9.y};
        const f32x4 rh9 = qhi ? (f32x4){c9.z, c9.w, c9.w, c9.w}
                              : (f32x4){c9.z, c9.w, Rx, Ry};
        __builtin_nontemporal_store(max4(lh9, rh9), (f32x4*)(o9 + (y0 + i) * W + x0));

        // pool13: out[x] = max(c13[x-4], c13[x], c13[x+4])
        f32x4 L13, R13;
        L13.x = dpp_shr1(c13.x); L13.y = dpp_shr1(c13.y);
        L13.z = dpp_shr1(c13.z); L13.w = dpp_shr1(c13.w);
        R13.x = dpp_shl1(c13.x); R13.y = dpp_shl1(c13.y);
        R13.z = dpp_shl1(c13.z); R13.w = dpp_shl1(c13.w);
        const f32x4 lh13 = qlo ? (f32x4){c13.x, c13.x, c13.x, c13.x} : L13;
        const f32x4 rh13 = qhi ? (f32x4){c13.w, c13.w, c13.w, c13.w} : R13;
        __builtin_nontemporal_store(max4(max4(lh13, c13), rh13),
                                    (f32x4*)(o13 + (y0 + i) * W + x0));
    }
}

extern "C" void kernel_launch(void* const* d_in, const int* in_sizes, int n_in,
                              void* d_out, int out_size, void* d_ws, size_t ws_size,
                              hipStream_t stream) {
    const float* x = (const float*)d_in[0];
    float* out = (float*)d_out;
    // 4096 images, one per block; no LDS, no barriers
    spp_kernel<<<dim3(4096), dim3(TPB), 0, stream>>>(x, out);
}